// Round 9
// baseline (351.165 us; speedup 1.0000x reference)
//
#include <hip/hip_runtime.h>
#include <cmath>

static constexpr float EPS = 1e-5f;
static constexpr float NEG = 0.2f;

typedef __attribute__((ext_vector_type(8))) short short8v;
typedef __attribute__((ext_vector_type(4))) short short4v;
typedef __attribute__((ext_vector_type(4))) float f32x4;
typedef __attribute__((ext_vector_type(2))) float f32x2;

__device__ inline unsigned short f2bf(float f) {
    union { float f; unsigned u; } v; v.f = f;
    unsigned r = v.u + 0x7FFF + ((v.u >> 16) & 1);   // RNE
    return (unsigned short)(r >> 16);
}
__device__ inline float bf2f(unsigned short u) {
    union { unsigned u; float f; } v; v.u = (unsigned)u << 16; return v.f;
}

// ---------------- fused setup: count + convert_x + convert_weights + walpha ----------------
__global__ void setup_kernel(const int* __restrict__ ei, int* __restrict__ cnt, int E, int n,
                             const float* __restrict__ x, unsigned short* __restrict__ xb,
                             const float* W1, const float* W2, const float* W3,
                             const float* W4, const float* W5,
                             unsigned short* T1, unsigned short* T2, unsigned short* T3,
                             unsigned short* TF, unsigned short* T5,
                             const float* as1, const float* ad1,
                             const float* as2, const float* ad2,
                             float* wa1, float* wa2) {
    int gid = blockIdx.x * 256 + threadIdx.x;
    if (gid < E) {                            // count
        atomicAdd(&cnt[ei[E + gid]], 1);
        return;
    }
    gid -= E;
    int n32 = n * 32;
    if (gid < n32) {                          // convert x -> bf16
        float4 v = *reinterpret_cast<const float4*>(&x[(size_t)gid * 4]);
        unsigned long long pk = (unsigned long long)f2bf(v.x)
                              | ((unsigned long long)f2bf(v.y) << 16)
                              | ((unsigned long long)f2bf(v.z) << 32)
                              | ((unsigned long long)f2bf(v.w) << 48);
        *reinterpret_cast<unsigned long long*>(&xb[(size_t)gid * 4]) = pk;
        return;
    }
    gid -= n32;
    if (gid < 212992) {                       // transpose+convert weights
        int idx = gid;
        if (idx < 8192) {                       // gcn1 [C=64][K=128]
            int c = idx / 128, k = idx % 128;
            T1[idx] = f2bf(W1[(size_t)k * 64 + c]);
        } else if (idx < 16384) {               // gcn2 [C=128][K=64]
            int j = idx - 8192, c = j / 64, k = j % 64;
            T2[j] = f2bf(W2[(size_t)k * 128 + c]);
        } else if (idx < 49152) {               // gat1 [256][128]
            int j = idx - 16384, c = j / 128, k = j % 128;
            T3[j] = f2bf(W3[(size_t)k * 256 + c]);
        } else if (idx < 180224) {              // gat2-mean [128][1024]
            int j = idx - 49152;
            int c = j / 1024, kk = j % 1024, h = kk >> 8, k = kk & 255;
            TF[j] = f2bf(0.25f * W4[(size_t)k * 512 + h * 128 + c]);
        } else {                                // fuse [128][256]
            int j = idx - 180224, c = j / 256, k = j % 256;
            T5[j] = f2bf(W5[(size_t)k * 128 + c]);
        }
        return;
    }
    gid -= 212992;
    if (gid < 1024) {                         // walpha1
        int k = gid >> 3, t = gid & 7, h = t >> 1;
        const float* a = (t & 1) ? ad1 : as1;
        float s = 0.f;
        for (int c = 0; c < 64; c++) s += W3[(size_t)k * 256 + h * 64 + c] * a[h * 64 + c];
        wa1[gid] = s;
    } else if (gid < 3072) {                  // walpha2
        int j = gid - 1024;
        int k = j >> 3, t = j & 7, h = t >> 1;
        const float* a = (t & 1) ? ad2 : as2;
        float s = 0.f;
        for (int c = 0; c < 128; c++) s += W4[(size_t)k * 512 + h * 128 + c] * a[h * 128 + c];
        wa2[j] = s;
    }
}

// ---------------- CSR scan ----------------
__global__ __launch_bounds__(256) void partial_kernel(const int* __restrict__ cnt,
                                                      int* __restrict__ partials, int n) {
    int tid = threadIdx.x, lane = tid & 63, wid = tid >> 6;
    int base = blockIdx.x * 1024 + tid * 4;
    int s = 0;
    if (base + 3 < n) {
        int4 v = *reinterpret_cast<const int4*>(&cnt[base]);
        s = v.x + v.y + v.z + v.w;
    } else {
        for (int j = 0; j < 4; j++) if (base + j < n) s += cnt[base + j];
    }
    #pragma unroll
    for (int o = 32; o; o >>= 1) s += __shfl_xor(s, o, 64);
    __shared__ int ws[4];
    if (lane == 0) ws[wid] = s;
    __syncthreads();
    if (tid == 0) partials[blockIdx.x] = ws[0] + ws[1] + ws[2] + ws[3];
}

__global__ void scanp_kernel(int* __restrict__ partials, int nb) {
    int lane = threadIdx.x;
    int v = (lane < nb) ? partials[lane] : 0;
    int s = v;
    #pragma unroll
    for (int o = 1; o < 64; o <<= 1) {
        int t = __shfl_up(s, o, 64);
        if (lane >= o) s += t;
    }
    if (lane < nb) partials[lane] = s - v;
}

__global__ __launch_bounds__(256) void scan2_kernel(const int* __restrict__ cnt,
                                                    const int* __restrict__ partials,
                                                    int* __restrict__ rowptr,
                                                    int* __restrict__ cursor,
                                                    float* __restrict__ dis, int n, int E) {
    int tid = threadIdx.x, lane = tid & 63, wid = tid >> 6;
    int base = blockIdx.x * 1024 + tid * 4;
    int v[4]; int s = 0;
    #pragma unroll
    for (int j = 0; j < 4; j++) { v[j] = (base + j < n) ? cnt[base + j] : 0; s += v[j]; }
    int ts = s;
    #pragma unroll
    for (int o = 1; o < 64; o <<= 1) {
        int t = __shfl_up(ts, o, 64);
        if (lane >= o) ts += t;
    }
    __shared__ int wsum[4];
    if (lane == 63) wsum[wid] = ts;
    __syncthreads();
    int woff = 0;
    for (int w = 0; w < wid; w++) woff += wsum[w];
    int excl = ts - s + woff + partials[blockIdx.x];
    #pragma unroll
    for (int j = 0; j < 4; j++) {
        int idx = base + j;
        if (idx < n) {
            rowptr[idx] = excl;
            cursor[idx] = excl;
            dis[idx] = rsqrtf((float)(v[j] + 1));
            excl += v[j];
        }
    }
    if (blockIdx.x == 0 && tid == 0) rowptr[n] = E;
}

__global__ void fill_kernel(const int* __restrict__ ei, int* __restrict__ cursor,
                            int* __restrict__ col, int E) {
    int e = blockIdx.x * 256 + threadIdx.x;
    if (e < E) {
        int d = ei[E + e];
        int pos = atomicAdd(&cursor[d], 1);
        col[pos] = ei[e];
    }
}

// ---------------- MFMA GEMM: out[M,C] = A[M,K](bf16) @ W (+bias), ACT: 0 none, 1 relu ----------------
template<int BM, int K, int C, bool OBF, int ACT>
__global__ __launch_bounds__(256) void mfma_gemm(const unsigned short* __restrict__ A,
                                                 const unsigned short* __restrict__ WT,
                                                 const float* __restrict__ bias,
                                                 void* __restrict__ outp, int M) {
    constexpr int BN = 64, BK = 64;
    constexpr int MF = BM / 64;    // m-frags per wave
    __shared__ unsigned short As[BM * BK];
    __shared__ unsigned short Ws[BN * BK];
    int tid = threadIdx.x;
    int wid = tid >> 6, lane = tid & 63;
    int m0 = blockIdx.x * BM;
    int n0 = blockIdx.y * BN;

    f32x4 acc[MF][4] = {};

    for (int k0 = 0; k0 < K; k0 += BK) {
        for (int i = tid; i < BM * (BK / 8); i += 256) {
            int row = i >> 3;
            int kk = (i & 7) * 8;
            int gr = m0 + row;
            short8v v = short8v{0, 0, 0, 0, 0, 0, 0, 0};
            if (gr < M) v = *reinterpret_cast<const short8v*>(&A[(size_t)gr * K + k0 + kk]);
            int byte = (kk * 2) ^ ((row & 7) << 4);
            *reinterpret_cast<short8v*>((char*)As + row * (BK * 2) + byte) = v;
        }
        for (int i = tid; i < BN * (BK / 8); i += 256) {
            int nrow = i >> 3;
            int kk = (i & 7) * 8;
            short8v v = *reinterpret_cast<const short8v*>(&WT[(size_t)(n0 + nrow) * K + k0 + kk]);
            int byte = (kk * 2) ^ ((nrow & 7) << 4);
            *reinterpret_cast<short8v*>((char*)Ws + nrow * (BK * 2) + byte) = v;
        }
        __syncthreads();
        #pragma unroll
        for (int kc = 0; kc < BK; kc += 32) {
            short8v afr[MF], bfr[4];
            int kk = kc + (lane >> 4) * 8;
            #pragma unroll
            for (int mf = 0; mf < MF; mf++) {
                int row = wid * (16 * MF) + mf * 16 + (lane & 15);
                int byte = (kk * 2) ^ ((row & 7) << 4);
                afr[mf] = *reinterpret_cast<const short8v*>((char*)As + row * (BK * 2) + byte);
            }
            #pragma unroll
            for (int nf = 0; nf < 4; nf++) {
                int nrow = nf * 16 + (lane & 15);
                int byte = (kk * 2) ^ ((nrow & 7) << 4);
                bfr[nf] = *reinterpret_cast<const short8v*>((char*)Ws + nrow * (BK * 2) + byte);
            }
            #pragma unroll
            for (int mf = 0; mf < MF; mf++)
                #pragma unroll
                for (int nf = 0; nf < 4; nf++)
                    acc[mf][nf] = __builtin_amdgcn_mfma_f32_16x16x32_bf16(
                        afr[mf], bfr[nf], acc[mf][nf], 0, 0, 0);
        }
        __syncthreads();
    }
    #pragma unroll
    for (int mf = 0; mf < MF; mf++) {
        #pragma unroll
        for (int nf = 0; nf < 4; nf++) {
            #pragma unroll
            for (int r = 0; r < 4; r++) {
                int row = m0 + wid * (16 * MF) + mf * 16 + (lane >> 4) * 4 + r;
                int colg = n0 + nf * 16 + (lane & 15);
                if (row < M) {
                    float v = acc[mf][nf][r];
                    if (bias) v += bias[colg];
                    if (ACT == 1) v = fmaxf(v, 0.f);
                    if constexpr (OBF)
                        ((unsigned short*)outp)[(size_t)row * C + colg] = f2bf(v);
                    else
                        ((float*)outp)[(size_t)row * C + colg] = v;
                }
            }
        }
    }
}

// ---------------- per-head GEMM (BM=64): g1[r, h*64+c] = ELU(agg1[r, h*128+:] @ W3_h + b) ----------------
__global__ __launch_bounds__(256) void gemm_head_kernel(const unsigned short* __restrict__ A,   // [M][512]
                                                        const unsigned short* __restrict__ WT3, // [256][128]
                                                        const float* __restrict__ bias,         // [256]
                                                        unsigned short* __restrict__ g1b, int M) {
    constexpr int BM = 64, BK = 64, K = 128;
    int head = blockIdx.y;
    __shared__ unsigned short As[BM * BK];
    __shared__ unsigned short Ws[64 * BK];
    int tid = threadIdx.x;
    int wid = tid >> 6, lane = tid & 63;
    int m0 = blockIdx.x * BM;

    f32x4 acc[4] = {};

    for (int k0 = 0; k0 < K; k0 += BK) {
        for (int i = tid; i < BM * (BK / 8); i += 256) {
            int row = i >> 3;
            int kk = (i & 7) * 8;
            int gr = m0 + row;
            short8v v = short8v{0, 0, 0, 0, 0, 0, 0, 0};
            if (gr < M) v = *reinterpret_cast<const short8v*>(&A[(size_t)gr * 512 + head * 128 + k0 + kk]);
            int byte = (kk * 2) ^ ((row & 7) << 4);
            *reinterpret_cast<short8v*>((char*)As + row * (BK * 2) + byte) = v;
        }
        for (int i = tid; i < 64 * (BK / 8); i += 256) {
            int nrow = i >> 3;
            int kk = (i & 7) * 8;
            short8v v = *reinterpret_cast<const short8v*>(&WT3[(size_t)(head * 64 + nrow) * 128 + k0 + kk]);
            int byte = (kk * 2) ^ ((nrow & 7) << 4);
            *reinterpret_cast<short8v*>((char*)Ws + nrow * (BK * 2) + byte) = v;
        }
        __syncthreads();
        #pragma unroll
        for (int kc = 0; kc < BK; kc += 32) {
            short8v afr, bfr[4];
            int kk = kc + (lane >> 4) * 8;
            {
                int row = wid * 16 + (lane & 15);
                int byte = (kk * 2) ^ ((row & 7) << 4);
                afr = *reinterpret_cast<const short8v*>((char*)As + row * (BK * 2) + byte);
            }
            #pragma unroll
            for (int nf = 0; nf < 4; nf++) {
                int nrow = nf * 16 + (lane & 15);
                int byte = (kk * 2) ^ ((nrow & 7) << 4);
                bfr[nf] = *reinterpret_cast<const short8v*>((char*)Ws + nrow * (BK * 2) + byte);
            }
            #pragma unroll
            for (int nf = 0; nf < 4; nf++)
                acc[nf] = __builtin_amdgcn_mfma_f32_16x16x32_bf16(afr, bfr[nf], acc[nf], 0, 0, 0);
        }
        __syncthreads();
    }
    #pragma unroll
    for (int nf = 0; nf < 4; nf++) {
        #pragma unroll
        for (int r = 0; r < 4; r++) {
            int row = m0 + wid * 16 + (lane >> 4) * 4 + r;
            int cl = head * 64 + nf * 16 + (lane & 15);
            if (row < M) {
                float v = acc[nf][r] + bias[cl];
                v = v > 0.f ? v : __expf(v) - 1.f;   // ELU
                g1b[(size_t)row * 256 + cl] = f2bf(v);
            }
        }
    }
}

// ---------------- GEMM + LayerNorm (BM=64, BN=128 full row) -> catb[:, coloff..] ----------------
template<int K>
__global__ __launch_bounds__(256) void gemm_ln_kernel(const unsigned short* __restrict__ A,
                                                      const unsigned short* __restrict__ WT,
                                                      const float* __restrict__ bias,
                                                      const float* __restrict__ gw,
                                                      const float* __restrict__ gb,
                                                      unsigned short* __restrict__ catb,
                                                      int coloff, int M) {
    constexpr int BM = 64, BN = 128, BK = 64;
    __shared__ unsigned short As[BM * BK];
    __shared__ unsigned short Ws[BN * BK];
    int tid = threadIdx.x;
    int wid = tid >> 6, lane = tid & 63;
    int m0 = blockIdx.x * BM;

    f32x4 acc[8] = {};

    for (int k0 = 0; k0 < K; k0 += BK) {
        for (int i = tid; i < BM * (BK / 8); i += 256) {
            int row = i >> 3;
            int kk = (i & 7) * 8;
            int gr = m0 + row;
            short8v v = short8v{0, 0, 0, 0, 0, 0, 0, 0};
            if (gr < M) v = *reinterpret_cast<const short8v*>(&A[(size_t)gr * K + k0 + kk]);
            int byte = (kk * 2) ^ ((row & 7) << 4);
            *reinterpret_cast<short8v*>((char*)As + row * (BK * 2) + byte) = v;
        }
        for (int i = tid; i < BN * (BK / 8); i += 256) {
            int nrow = i >> 3;
            int kk = (i & 7) * 8;
            short8v v = *reinterpret_cast<const short8v*>(&WT[(size_t)nrow * K + k0 + kk]);
            int byte = (kk * 2) ^ ((nrow & 7) << 4);
            *reinterpret_cast<short8v*>((char*)Ws + nrow * (BK * 2) + byte) = v;
        }
        __syncthreads();
        #pragma unroll
        for (int kc = 0; kc < BK; kc += 32) {
            short8v afr, bfr[8];
            int kk = kc + (lane >> 4) * 8;
            {
                int row = wid * 16 + (lane & 15);
                int byte = (kk * 2) ^ ((row & 7) << 4);
                afr = *reinterpret_cast<const short8v*>((char*)As + row * (BK * 2) + byte);
            }
            #pragma unroll
            for (int nf = 0; nf < 8; nf++) {
                int nrow = nf * 16 + (lane & 15);
                int byte = (kk * 2) ^ ((nrow & 7) << 4);
                bfr[nf] = *reinterpret_cast<const short8v*>((char*)Ws + nrow * (BK * 2) + byte);
            }
            #pragma unroll
            for (int nf = 0; nf < 8; nf++)
                acc[nf] = __builtin_amdgcn_mfma_f32_16x16x32_bf16(afr, bfr[nf], acc[nf], 0, 0, 0);
        }
        __syncthreads();
    }
    // epilogue: +bias, LN over 128 cols (16-lane group holds full row), bf16 store
    int cb = lane & 15;
    float gwv[8], gbv[8], bv[8];
    #pragma unroll
    for (int nf = 0; nf < 8; nf++) {
        int c = nf * 16 + cb;
        gwv[nf] = gw[c]; gbv[nf] = gb[c]; bv[nf] = bias[c];
    }
    #pragma unroll
    for (int r = 0; r < 4; r++) {
        int row = m0 + wid * 16 + (lane >> 4) * 4 + r;
        float v[8]; float sm = 0.f, sq = 0.f;
        #pragma unroll
        for (int nf = 0; nf < 8; nf++) {
            v[nf] = acc[nf][r] + bv[nf];
            sm += v[nf]; sq += v[nf] * v[nf];
        }
        #pragma unroll
        for (int o = 1; o < 16; o <<= 1) { sm += __shfl_xor(sm, o, 64); sq += __shfl_xor(sq, o, 64); }
        float mu = sm * (1.f / 128.f);
        float var = sq * (1.f / 128.f) - mu * mu;
        float rs = rsqrtf(var + EPS);
        if (row < M) {
            #pragma unroll
            for (int nf = 0; nf < 8; nf++)
                catb[(size_t)row * 256 + coloff + nf * 16 + cb] =
                    f2bf((v[nf] - mu) * rs * gwv[nf] + gbv[nf]);
        }
    }
}

// ---------------- alpha from features: as_/ad_[n,4] = F[n,K] @ walpha[K][8] ----------------
template<int K>
__global__ __launch_bounds__(256) void alpha_x_kernel(const unsigned short* __restrict__ F,
                                                      const float* __restrict__ wa,
                                                      float* __restrict__ as_, float* __restrict__ ad_, int n) {
    constexpr int PL = K / 64;
    int wid = threadIdx.x >> 6, lane = threadIdx.x & 63;
    int node = blockIdx.x * 4 + wid;
    if (node >= n) return;
    float p[8] = {0, 0, 0, 0, 0, 0, 0, 0};
    const unsigned short* fr = F + (size_t)node * K + lane * PL;
    #pragma unroll
    for (int j = 0; j < PL; j++) {
        float v = bf2f(fr[j]);
        const float4* w4 = reinterpret_cast<const float4*>(wa + (size_t)(lane * PL + j) * 8);
        float4 wA = w4[0], wB = w4[1];
        p[0] += v * wA.x; p[1] += v * wA.y; p[2] += v * wA.z; p[3] += v * wA.w;
        p[4] += v * wB.x; p[5] += v * wB.y; p[6] += v * wB.z; p[7] += v * wB.w;
    }
    #pragma unroll
    for (int o = 1; o < 64; o <<= 1) {
        #pragma unroll
        for (int t = 0; t < 8; t++) p[t] += __shfl_xor(p[t], o, 64);
    }
    if (lane == 0) {
        #pragma unroll
        for (int t = 0; t < 8; t++) {
            if (t & 1) ad_[(size_t)node * 4 + (t >> 1)] = p[t];
            else       as_[(size_t)node * 4 + (t >> 1)] = p[t];
        }
    }
}

// ---------------- merged layer1: GCN P(x) aggregate + GAT-l1 aggregate (ONE gather stream) ----------------
__global__ __launch_bounds__(256) void prop1_agg1_kernel(const unsigned short* __restrict__ xb,   // [n][128]
                                                         const float* __restrict__ dis,
                                                         const float* __restrict__ as_,
                                                         const float* __restrict__ ad_,
                                                         const int* __restrict__ rowptr,
                                                         const int* __restrict__ col,
                                                         unsigned short* __restrict__ aggx,       // [n][128] = P(x)
                                                         unsigned short* __restrict__ agg,        // [n][512]
                                                         int n) {
    constexpr int CAP = 96;
    __shared__ float ex[4][CAP][4];
    __shared__ float dsl[4][CAP];
    __shared__ int scol[4][CAP];
    int wid = threadIdx.x >> 6, lane = threadIdx.x & 63;
    int node = blockIdx.x * 4 + wid;
    if (node >= n) return;
    int b0 = rowptr[node];
    int cnt = rowptr[node + 1] - b0;
    float4 adv = *reinterpret_cast<const float4*>(&ad_[(size_t)node * 4]);
    float p0 = 0, p1 = 0, p2 = 0, p3 = 0;
    for (int i = lane; i <= cnt; i += 64) {
        int s = (i == cnt) ? node : col[b0 + i];
        float4 asv = *reinterpret_cast<const float4*>(&as_[(size_t)s * 4]);
        float e0 = asv.x + adv.x; e0 = e0 > 0.f ? e0 : NEG * e0; float x0 = __expf(e0);
        float e1 = asv.y + adv.y; e1 = e1 > 0.f ? e1 : NEG * e1; float x1 = __expf(e1);
        float e2 = asv.z + adv.z; e2 = e2 > 0.f ? e2 : NEG * e2; float x2 = __expf(e2);
        float e3 = asv.w + adv.w; e3 = e3 > 0.f ? e3 : NEG * e3; float x3 = __expf(e3);
        if (i < CAP) {
            ex[wid][i][0] = x0; ex[wid][i][1] = x1; ex[wid][i][2] = x2; ex[wid][i][3] = x3;
            scol[wid][i] = s;
            dsl[wid][i] = dis[s];
        }
        p0 += x0; p1 += x1; p2 += x2; p3 += x3;
    }
    #pragma unroll
    for (int o = 1; o < 64; o <<= 1) {
        p0 += __shfl_xor(p0, o, 64); p1 += __shfl_xor(p1, o, 64);
        p2 += __shfl_xor(p2, o, 64); p3 += __shfl_xor(p3, o, 64);
    }
    float inv0 = 1.f / p0, inv1 = 1.f / p1, inv2 = 1.f / p2, inv3 = 1.f / p3;
    // normalize cached weights in LDS (edge-parallel)
    for (int i = lane; i <= cnt && i < CAP; i += 64) {
        ex[wid][i][0] *= inv0; ex[wid][i][1] *= inv1;
        ex[wid][i][2] *= inv2; ex[wid][i][3] *= inv3;
    }
    __builtin_amdgcn_wave_barrier();
    f32x2 g2 = {0.f, 0.f};
    f32x2 ac2[4] = {};
    for (int i = 0; i <= cnt; i++) {
        int s; float w0, w1, w2, w3, dsv;
        if (i < CAP) {
            s = scol[wid][i];
            float4 e = *reinterpret_cast<const float4*>(&ex[wid][i][0]);
            w0 = e.x; w1 = e.y; w2 = e.z; w3 = e.w;
            dsv = dsl[wid][i];
        } else {
            s = (i == cnt) ? node : col[b0 + i];
            float4 asv = *reinterpret_cast<const float4*>(&as_[(size_t)s * 4]);
            float e0 = asv.x + adv.x; e0 = e0 > 0.f ? e0 : NEG * e0;
            float e1 = asv.y + adv.y; e1 = e1 > 0.f ? e1 : NEG * e1;
            float e2 = asv.z + adv.z; e2 = e2 > 0.f ? e2 : NEG * e2;
            float e3 = asv.w + adv.w; e3 = e3 > 0.f ? e3 : NEG * e3;
            w0 = __expf(e0) * inv0; w1 = __expf(e1) * inv1;
            w2 = __expf(e2) * inv2; w3 = __expf(e3) * inv3;
            dsv = dis[s];
        }
        unsigned gv = *reinterpret_cast<const unsigned*>(&xb[(size_t)s * 128 + lane * 2]);
        f32x2 f;
        f.x = bf2f((unsigned short)(gv & 0xFFFF));
        f.y = bf2f((unsigned short)(gv >> 16));
        g2 += dsv * f;
        ac2[0] += w0 * f;
        ac2[1] += w1 * f;
        ac2[2] += w2 * f;
        ac2[3] += w3 * f;
    }
    float dd = dis[node];
    unsigned pkg = (unsigned)f2bf(dd * g2.x) | ((unsigned)f2bf(dd * g2.y) << 16);
    *reinterpret_cast<unsigned*>(&aggx[(size_t)node * 128 + lane * 2]) = pkg;
    #pragma unroll
    for (int h = 0; h < 4; h++) {
        unsigned pk = (unsigned)f2bf(ac2[h].x) | ((unsigned)f2bf(ac2[h].y) << 16);
        *reinterpret_cast<unsigned*>(&agg[(size_t)node * 512 + h * 128 + lane * 2]) = pk;
    }
}

// ---------------- merged layer2: GCN P(h) aggregate + GAT-l2 aggregate ----------------
__global__ __launch_bounds__(256) void prop2_agg2_kernel(const unsigned short* __restrict__ g1b,  // [n][256]
                                                         const unsigned short* __restrict__ hb,   // [n][64]
                                                         const float* __restrict__ dis,
                                                         const float* __restrict__ as_,
                                                         const float* __restrict__ ad_,
                                                         const int* __restrict__ rowptr,
                                                         const int* __restrict__ col,
                                                         unsigned short* __restrict__ aggh,       // [n][64] = P(h)
                                                         unsigned short* __restrict__ agg,        // [n][1024]
                                                         int n) {
    constexpr int CAP = 96;
    __shared__ float ex[4][CAP][4];
    __shared__ float dsl[4][CAP];
    __shared__ int scol[4][CAP];
    int wid = threadIdx.x >> 6, lane = threadIdx.x & 63;
    int node = blockIdx.x * 4 + wid;
    if (node >= n) return;
    int b0 = rowptr[node];
    int cnt = rowptr[node + 1] - b0;
    float4 adv = *reinterpret_cast<const float4*>(&ad_[(size_t)node * 4]);
    float p0 = 0, p1 = 0, p2 = 0, p3 = 0;
    for (int i = lane; i <= cnt; i += 64) {
        int s = (i == cnt) ? node : col[b0 + i];
        float4 asv = *reinterpret_cast<const float4*>(&as_[(size_t)s * 4]);
        float e0 = asv.x + adv.x; e0 = e0 > 0.f ? e0 : NEG * e0; float x0 = __expf(e0);
        float e1 = asv.y + adv.y; e1 = e1 > 0.f ? e1 : NEG * e1; float x1 = __expf(e1);
        float e2 = asv.z + adv.z; e2 = e2 > 0.f ? e2 : NEG * e2; float x2 = __expf(e2);
        float e3 = asv.w + adv.w; e3 = e3 > 0.f ? e3 : NEG * e3; float x3 = __expf(e3);
        if (i < CAP) {
            ex[wid][i][0] = x0; ex[wid][i][1] = x1; ex[wid][i][2] = x2; ex[wid][i][3] = x3;
            scol[wid][i] = s;
            dsl[wid][i] = dis[s];
        }
        p0 += x0; p1 += x1; p2 += x2; p3 += x3;
    }
    #pragma unroll
    for (int o = 1; o < 64; o <<= 1) {
        p0 += __shfl_xor(p0, o, 64); p1 += __shfl_xor(p1, o, 64);
        p2 += __shfl_xor(p2, o, 64); p3 += __shfl_xor(p3, o, 64);
    }
    float inv0 = 1.f / p0, inv1 = 1.f / p1, inv2 = 1.f / p2, inv3 = 1.f / p3;
    for (int i = lane; i <= cnt && i < CAP; i += 64) {
        ex[wid][i][0] *= inv0; ex[wid][i][1] *= inv1;
        ex[wid][i][2] *= inv2; ex[wid][i][3] *= inv3;
    }
    __builtin_amdgcn_wave_barrier();
    float hacc = 0.f;
    f32x2 ac2[4][2] = {};
    for (int i = 0; i <= cnt; i++) {
        int s; float w0, w1, w2, w3, dsv;
        if (i < CAP) {
            s = scol[wid][i];
            float4 e = *reinterpret_cast<const float4*>(&ex[wid][i][0]);
            w0 = e.x; w1 = e.y; w2 = e.z; w3 = e.w;
            dsv = dsl[wid][i];
        } else {
            s = (i == cnt) ? node : col[b0 + i];
            float4 asv = *reinterpret_cast<const float4*>(&as_[(size_t)s * 4]);
            float e0 = asv.x + adv.x; e0 = e0 > 0.f ? e0 : NEG * e0;
            float e1 = asv.y + adv.y; e1 = e1 > 0.f ? e1 : NEG * e1;
            float e2 = asv.z + adv.z; e2 = e2 > 0.f ? e2 : NEG * e2;
            float e3 = asv.w + adv.w; e3 = e3 > 0.f ? e3 : NEG * e3;
            w0 = __expf(e0) * inv0; w1 = __expf(e1) * inv1;
            w2 = __expf(e2) * inv2; w3 = __expf(e3) * inv3;
            dsv = dis[s];
        }
        short4v v = *reinterpret_cast<const short4v*>(&g1b[(size_t)s * 256 + lane * 4]);
        float hv = bf2f(hb[(size_t)s * 64 + lane]);
        hacc += dsv * hv;
        f32x2 fa, fb;
        fa.x = bf2f((unsigned short)v[0]); fa.y = bf2f((unsigned short)v[1]);
        fb.x = bf2f((unsigned short)v[2]); fb.y = bf2f((unsigned short)v[3]);
        ac2[0][0] += w0 * fa; ac2[0][1] += w0 * fb;
        ac2[1][0] += w1 * fa; ac2[1][1] += w1 * fb;
        ac2[2][0] += w2 * fa; ac2[2][1] += w2 * fb;
        ac2[3][0] += w3 * fa; ac2[3][1] += w3 * fb;
    }
    float dd = dis[node];
    aggh[(size_t)node * 64 + lane] = f2bf(dd * hacc);
    #pragma unroll
    for (int h = 0; h < 4; h++) {
        short4v o4;
        o4[0] = (short)f2bf(ac2[h][0].x); o4[1] = (short)f2bf(ac2[h][0].y);
        o4[2] = (short)f2bf(ac2[h][1].x); o4[3] = (short)f2bf(ac2[h][1].y);
        *reinterpret_cast<short4v*>(&agg[(size_t)node * 1024 + h * 256 + lane * 4]) = o4;
    }
}

// ---------------- launch ----------------
extern "C" void kernel_launch(void* const* d_in, const int* in_sizes, int n_in,
                              void* d_out, int out_size, void* d_ws, size_t ws_size,
                              hipStream_t stream) {
    const float* x      = (const float*)d_in[0];
    const int*   ei     = (const int*)d_in[1];
    const float* W_gcn1 = (const float*)d_in[2];
    const float* b_gcn1 = (const float*)d_in[3];
    const float* W_gcn2 = (const float*)d_in[4];
    const float* b_gcn2 = (const float*)d_in[5];
    const float* W_gat1 = (const float*)d_in[6];
    const float* a_src1 = (const float*)d_in[7];
    const float* a_dst1 = (const float*)d_in[8];
    const float* b_gat1 = (const float*)d_in[9];
    const float* W_gat2 = (const float*)d_in[10];
    const float* a_src2 = (const float*)d_in[11];
    const float* a_dst2 = (const float*)d_in[12];
    const float* b_gat2 = (const float*)d_in[13];
    const float* g_gcn  = (const float*)d_in[14];
    const float* bt_gcn = (const float*)d_in[15];
    const float* g_gat  = (const float*)d_in[16];
    const float* bt_gat = (const float*)d_in[17];
    const float* W_fuse = (const float*)d_in[18];
    const float* b_fuse = (const float*)d_in[19];
    float* out = (float*)d_out;

    const int n = in_sizes[0] / 128;
    const int E = in_sizes[1] / 2;

    char* ws = (char*)d_ws;
    size_t off = 0;
    auto alloc = [&](size_t bytes) -> char* {
        char* p = ws + off;
        off += (bytes + 255) & ~(size_t)255;
        return p;
    };
    int*   cnt      = (int*)alloc((size_t)n * 4);
    int*   rowptr   = (int*)alloc((size_t)(n + 1) * 4);
    int*   cursor   = (int*)alloc((size_t)n * 4);
    int*   col      = (int*)alloc((size_t)E * 4);
    int*   partials = (int*)alloc(64 * 4);
    float* dis      = (float*)alloc((size_t)n * 4);
    float* as_      = (float*)alloc((size_t)n * 16);
    float* ad_      = (float*)alloc((size_t)n * 16);
    float* wa1      = (float*)alloc(1024 * 4);
    float* wa2      = (float*)alloc(2048 * 4);
    unsigned short* xb   = (unsigned short*)alloc((size_t)n * 128 * 2);
    unsigned short* WT1  = (unsigned short*)alloc(8192 * 2);
    unsigned short* WT2  = (unsigned short*)alloc(8192 * 2);
    unsigned short* WT3  = (unsigned short*)alloc(32768 * 2);
    unsigned short* WTF  = (unsigned short*)alloc(131072 * 2);
    unsigned short* WT5  = (unsigned short*)alloc(32768 * 2);
    // BIG (n*1024 bf16 = agg2b). Sub-lease while agg2 not yet live:
    //   agg1b = BIG[0, n*512) ; aggx1 = BIG[n*512, n*640)
    // hb/aggh OUTSIDE BIG (hb read while agg2b is written).
    unsigned short* BIG   = (unsigned short*)alloc((size_t)n * 1024 * 2);
    unsigned short* agg2b = BIG;
    unsigned short* agg1b = BIG;
    unsigned short* aggx1 = BIG + (size_t)n * 512;
    unsigned short* hb    = (unsigned short*)alloc((size_t)n * 64 * 2);
    unsigned short* aggh  = (unsigned short*)alloc((size_t)n * 64 * 2);
    unsigned short* g1b   = (unsigned short*)alloc((size_t)n * 256 * 2);
    unsigned short* catb  = (unsigned short*)alloc((size_t)n * 256 * 2);

    const int nb = (n + 1023) / 1024;

    // setup
    hipMemsetAsync(cnt, 0, (size_t)n * 4, stream);
    {
        long long total = (long long)E + (long long)n * 32 + 212992 + 3072;
        int blocks = (int)((total + 255) / 256);
        setup_kernel<<<blocks, 256, 0, stream>>>(ei, cnt, E, n, x, xb,
            W_gcn1, W_gcn2, W_gat1, W_gat2, W_fuse, WT1, WT2, WT3, WTF, WT5,
            a_src1, a_dst1, a_src2, a_dst2, wa1, wa2);
    }
    partial_kernel<<<nb, 256, 0, stream>>>(cnt, partials, n);
    scanp_kernel<<<1, 64, 0, stream>>>(partials, nb);
    scan2_kernel<<<nb, 256, 0, stream>>>(cnt, partials, rowptr, cursor, dis, n, E);
    fill_kernel<<<(E + 255) / 256, 256, 0, stream>>>(ei, cursor, col, E);

    int gm64 = (n + 63) / 64;
    int gn4 = (n + 3) / 4;

    // layer 1: one gather pass over xb feeds both branches
    alpha_x_kernel<128><<<gn4, 256, 0, stream>>>(xb, wa1, as_, ad_, n);
    prop1_agg1_kernel<<<gn4, 256, 0, stream>>>(xb, dis, as_, ad_, rowptr, col, aggx1, agg1b, n);
    // post-GEMMs: h = relu(P(x)@W1 + b1); g1 = ELU(agg1@W3 + b_gat1)
    mfma_gemm<64, 128, 64, true, 1><<<dim3(gm64, 1), 256, 0, stream>>>(aggx1, WT1, b_gcn1, hb, n);
    gemm_head_kernel<<<dim3(gm64, 4), 256, 0, stream>>>(agg1b, WT3, b_gat1, g1b, n);
    // layer 2
    alpha_x_kernel<256><<<gn4, 256, 0, stream>>>(g1b, wa2, as_, ad_, n);
    prop2_agg2_kernel<<<gn4, 256, 0, stream>>>(g1b, hb, dis, as_, ad_, rowptr, col, aggh, agg2b, n);
    // post-GEMMs with fused LN -> catb halves
    gemm_ln_kernel<64><<<gm64, 256, 0, stream>>>(aggh, WT2, b_gcn2, g_gcn, bt_gcn, catb, 0, n);
    gemm_ln_kernel<1024><<<gm64, 256, 0, stream>>>(agg2b, WTF, b_gat2, g_gat, bt_gat, catb, 128, n);

    // fuse
    mfma_gemm<64, 256, 128, false, 0><<<dim3(gm64, 2), 256, 0, stream>>>(catb, WT5, b_fuse, out, n);
}

// Round 10
// 343.901 us; speedup vs baseline: 1.0211x; 1.0211x over previous
//
#include <hip/hip_runtime.h>
#include <cmath>

static constexpr float EPS = 1e-5f;
static constexpr float NEG = 0.2f;

typedef __attribute__((ext_vector_type(8))) short short8v;
typedef __attribute__((ext_vector_type(4))) short short4v;
typedef __attribute__((ext_vector_type(4))) float f32x4;
typedef __attribute__((ext_vector_type(2))) float f32x2;

__device__ inline unsigned short f2bf(float f) {
    union { float f; unsigned u; } v; v.f = f;
    unsigned r = v.u + 0x7FFF + ((v.u >> 16) & 1);   // RNE
    return (unsigned short)(r >> 16);
}
__device__ inline float bf2f(unsigned short u) {
    union { unsigned u; float f; } v; v.u = (unsigned)u << 16; return v.f;
}

// ---------------- fused setup: count + convert_x + convert_weights + walpha ----------------
__global__ void setup_kernel(const int* __restrict__ ei, int* __restrict__ cnt, int E, int n,
                             const float* __restrict__ x, unsigned short* __restrict__ xb,
                             const float* W1, const float* W2, const float* W3,
                             const float* W4, const float* W5,
                             unsigned short* T1, unsigned short* T2, unsigned short* T3,
                             unsigned short* TF, unsigned short* T5,
                             const float* as1, const float* ad1,
                             const float* as2, const float* ad2,
                             float* wa1, float* wa2) {
    int gid = blockIdx.x * 256 + threadIdx.x;
    if (gid < E) {                            // count
        atomicAdd(&cnt[ei[E + gid]], 1);
        return;
    }
    gid -= E;
    int n32 = n * 32;
    if (gid < n32) {                          // convert x -> bf16
        float4 v = *reinterpret_cast<const float4*>(&x[(size_t)gid * 4]);
        unsigned long long pk = (unsigned long long)f2bf(v.x)
                              | ((unsigned long long)f2bf(v.y) << 16)
                              | ((unsigned long long)f2bf(v.z) << 32)
                              | ((unsigned long long)f2bf(v.w) << 48);
        *reinterpret_cast<unsigned long long*>(&xb[(size_t)gid * 4]) = pk;
        return;
    }
    gid -= n32;
    if (gid < 212992) {                       // transpose+convert weights
        int idx = gid;
        if (idx < 8192) {                       // gcn1 [C=64][K=128]
            int c = idx / 128, k = idx % 128;
            T1[idx] = f2bf(W1[(size_t)k * 64 + c]);
        } else if (idx < 16384) {               // gcn2 [C=128][K=64]
            int j = idx - 8192, c = j / 64, k = j % 64;
            T2[j] = f2bf(W2[(size_t)k * 128 + c]);
        } else if (idx < 49152) {               // gat1 [256][128]
            int j = idx - 16384, c = j / 128, k = j % 128;
            T3[j] = f2bf(W3[(size_t)k * 256 + c]);
        } else if (idx < 180224) {              // gat2-mean [128][1024]
            int j = idx - 49152;
            int c = j / 1024, kk = j % 1024, h = kk >> 8, k = kk & 255;
            TF[j] = f2bf(0.25f * W4[(size_t)k * 512 + h * 128 + c]);
        } else {                                // fuse [128][256]
            int j = idx - 180224, c = j / 256, k = j % 256;
            T5[j] = f2bf(W5[(size_t)k * 128 + c]);
        }
        return;
    }
    gid -= 212992;
    if (gid < 1024) {                         // walpha1
        int k = gid >> 3, t = gid & 7, h = t >> 1;
        const float* a = (t & 1) ? ad1 : as1;
        float s = 0.f;
        for (int c = 0; c < 64; c++) s += W3[(size_t)k * 256 + h * 64 + c] * a[h * 64 + c];
        wa1[gid] = s;
    } else if (gid < 3072) {                  // walpha2
        int j = gid - 1024;
        int k = j >> 3, t = j & 7, h = t >> 1;
        const float* a = (t & 1) ? ad2 : as2;
        float s = 0.f;
        for (int c = 0; c < 128; c++) s += W4[(size_t)k * 512 + h * 128 + c] * a[h * 128 + c];
        wa2[j] = s;
    }
}

// ---------------- CSR scan ----------------
__global__ __launch_bounds__(256) void partial_kernel(const int* __restrict__ cnt,
                                                      int* __restrict__ partials, int n) {
    int tid = threadIdx.x, lane = tid & 63, wid = tid >> 6;
    int base = blockIdx.x * 1024 + tid * 4;
    int s = 0;
    if (base + 3 < n) {
        int4 v = *reinterpret_cast<const int4*>(&cnt[base]);
        s = v.x + v.y + v.z + v.w;
    } else {
        for (int j = 0; j < 4; j++) if (base + j < n) s += cnt[base + j];
    }
    #pragma unroll
    for (int o = 32; o; o >>= 1) s += __shfl_xor(s, o, 64);
    __shared__ int ws[4];
    if (lane == 0) ws[wid] = s;
    __syncthreads();
    if (tid == 0) partials[blockIdx.x] = ws[0] + ws[1] + ws[2] + ws[3];
}

__global__ void scanp_kernel(int* __restrict__ partials, int nb) {
    int lane = threadIdx.x;
    int v = (lane < nb) ? partials[lane] : 0;
    int s = v;
    #pragma unroll
    for (int o = 1; o < 64; o <<= 1) {
        int t = __shfl_up(s, o, 64);
        if (lane >= o) s += t;
    }
    if (lane < nb) partials[lane] = s - v;
}

__global__ __launch_bounds__(256) void scan2_kernel(const int* __restrict__ cnt,
                                                    const int* __restrict__ partials,
                                                    int* __restrict__ rowptr,
                                                    int* __restrict__ cursor,
                                                    float* __restrict__ dis, int n, int E) {
    int tid = threadIdx.x, lane = tid & 63, wid = tid >> 6;
    int base = blockIdx.x * 1024 + tid * 4;
    int v[4]; int s = 0;
    #pragma unroll
    for (int j = 0; j < 4; j++) { v[j] = (base + j < n) ? cnt[base + j] : 0; s += v[j]; }
    int ts = s;
    #pragma unroll
    for (int o = 1; o < 64; o <<= 1) {
        int t = __shfl_up(ts, o, 64);
        if (lane >= o) ts += t;
    }
    __shared__ int wsum[4];
    if (lane == 63) wsum[wid] = ts;
    __syncthreads();
    int woff = 0;
    for (int w = 0; w < wid; w++) woff += wsum[w];
    int excl = ts - s + woff + partials[blockIdx.x];
    #pragma unroll
    for (int j = 0; j < 4; j++) {
        int idx = base + j;
        if (idx < n) {
            rowptr[idx] = excl;
            cursor[idx] = excl;
            dis[idx] = rsqrtf((float)(v[j] + 1));
            excl += v[j];
        }
    }
    if (blockIdx.x == 0 && tid == 0) rowptr[n] = E;
}

__global__ void fill_kernel(const int* __restrict__ ei, int* __restrict__ cursor,
                            int* __restrict__ col, int E) {
    int e = blockIdx.x * 256 + threadIdx.x;
    if (e < E) {
        int d = ei[E + e];
        int pos = atomicAdd(&cursor[d], 1);
        col[pos] = ei[e];
    }
}

// ---------------- MFMA GEMM: out[M,C] = A[M,K](bf16) @ W (+bias), ACT: 0 none, 1 relu ----------------
// rowscale: optional per-row scale applied AFTER activation (used to fold dis into hb).
template<int BM, int K, int C, bool OBF, int ACT>
__global__ __launch_bounds__(256) void mfma_gemm(const unsigned short* __restrict__ A,
                                                 const unsigned short* __restrict__ WT,
                                                 const float* __restrict__ bias,
                                                 const float* __restrict__ rowscale,
                                                 void* __restrict__ outp, int M) {
    constexpr int BN = 64, BK = 64;
    constexpr int MF = BM / 64;    // m-frags per wave
    __shared__ unsigned short As[BM * BK];
    __shared__ unsigned short Ws[BN * BK];
    int tid = threadIdx.x;
    int wid = tid >> 6, lane = tid & 63;
    int m0 = blockIdx.x * BM;
    int n0 = blockIdx.y * BN;

    f32x4 acc[MF][4] = {};

    for (int k0 = 0; k0 < K; k0 += BK) {
        for (int i = tid; i < BM * (BK / 8); i += 256) {
            int row = i >> 3;
            int kk = (i & 7) * 8;
            int gr = m0 + row;
            short8v v = short8v{0, 0, 0, 0, 0, 0, 0, 0};
            if (gr < M) v = *reinterpret_cast<const short8v*>(&A[(size_t)gr * K + k0 + kk]);
            int byte = (kk * 2) ^ ((row & 7) << 4);
            *reinterpret_cast<short8v*>((char*)As + row * (BK * 2) + byte) = v;
        }
        for (int i = tid; i < BN * (BK / 8); i += 256) {
            int nrow = i >> 3;
            int kk = (i & 7) * 8;
            short8v v = *reinterpret_cast<const short8v*>(&WT[(size_t)(n0 + nrow) * K + k0 + kk]);
            int byte = (kk * 2) ^ ((nrow & 7) << 4);
            *reinterpret_cast<short8v*>((char*)Ws + nrow * (BK * 2) + byte) = v;
        }
        __syncthreads();
        #pragma unroll
        for (int kc = 0; kc < BK; kc += 32) {
            short8v afr[MF], bfr[4];
            int kk = kc + (lane >> 4) * 8;
            #pragma unroll
            for (int mf = 0; mf < MF; mf++) {
                int row = wid * (16 * MF) + mf * 16 + (lane & 15);
                int byte = (kk * 2) ^ ((row & 7) << 4);
                afr[mf] = *reinterpret_cast<const short8v*>((char*)As + row * (BK * 2) + byte);
            }
            #pragma unroll
            for (int nf = 0; nf < 4; nf++) {
                int nrow = nf * 16 + (lane & 15);
                int byte = (kk * 2) ^ ((nrow & 7) << 4);
                bfr[nf] = *reinterpret_cast<const short8v*>((char*)Ws + nrow * (BK * 2) + byte);
            }
            #pragma unroll
            for (int mf = 0; mf < MF; mf++)
                #pragma unroll
                for (int nf = 0; nf < 4; nf++)
                    acc[mf][nf] = __builtin_amdgcn_mfma_f32_16x16x32_bf16(
                        afr[mf], bfr[nf], acc[mf][nf], 0, 0, 0);
        }
        __syncthreads();
    }
    #pragma unroll
    for (int mf = 0; mf < MF; mf++) {
        #pragma unroll
        for (int nf = 0; nf < 4; nf++) {
            #pragma unroll
            for (int r = 0; r < 4; r++) {
                int row = m0 + wid * (16 * MF) + mf * 16 + (lane >> 4) * 4 + r;
                int colg = n0 + nf * 16 + (lane & 15);
                if (row < M) {
                    float v = acc[mf][nf][r];
                    if (bias) v += bias[colg];
                    if (ACT == 1) v = fmaxf(v, 0.f);
                    if (rowscale) v *= rowscale[row];
                    if constexpr (OBF)
                        ((unsigned short*)outp)[(size_t)row * C + colg] = f2bf(v);
                    else
                        ((float*)outp)[(size_t)row * C + colg] = v;
                }
            }
        }
    }
}

// ---------------- per-head GEMM (BM=64): g1[r, h*64+c] = ELU(agg1[r, h*128+:] @ W3_h + b) ----------------
__global__ __launch_bounds__(256) void gemm_head_kernel(const unsigned short* __restrict__ A,   // [M][512]
                                                        const unsigned short* __restrict__ WT3, // [256][128]
                                                        const float* __restrict__ bias,         // [256]
                                                        unsigned short* __restrict__ g1b, int M) {
    constexpr int BM = 64, BK = 64, K = 128;
    int head = blockIdx.y;
    __shared__ unsigned short As[BM * BK];
    __shared__ unsigned short Ws[64 * BK];
    int tid = threadIdx.x;
    int wid = tid >> 6, lane = tid & 63;
    int m0 = blockIdx.x * BM;

    f32x4 acc[4] = {};

    for (int k0 = 0; k0 < K; k0 += BK) {
        for (int i = tid; i < BM * (BK / 8); i += 256) {
            int row = i >> 3;
            int kk = (i & 7) * 8;
            int gr = m0 + row;
            short8v v = short8v{0, 0, 0, 0, 0, 0, 0, 0};
            if (gr < M) v = *reinterpret_cast<const short8v*>(&A[(size_t)gr * 512 + head * 128 + k0 + kk]);
            int byte = (kk * 2) ^ ((row & 7) << 4);
            *reinterpret_cast<short8v*>((char*)As + row * (BK * 2) + byte) = v;
        }
        for (int i = tid; i < 64 * (BK / 8); i += 256) {
            int nrow = i >> 3;
            int kk = (i & 7) * 8;
            short8v v = *reinterpret_cast<const short8v*>(&WT3[(size_t)(head * 64 + nrow) * 128 + k0 + kk]);
            int byte = (kk * 2) ^ ((nrow & 7) << 4);
            *reinterpret_cast<short8v*>((char*)Ws + nrow * (BK * 2) + byte) = v;
        }
        __syncthreads();
        #pragma unroll
        for (int kc = 0; kc < BK; kc += 32) {
            short8v afr, bfr[4];
            int kk = kc + (lane >> 4) * 8;
            {
                int row = wid * 16 + (lane & 15);
                int byte = (kk * 2) ^ ((row & 7) << 4);
                afr = *reinterpret_cast<const short8v*>((char*)As + row * (BK * 2) + byte);
            }
            #pragma unroll
            for (int nf = 0; nf < 4; nf++) {
                int nrow = nf * 16 + (lane & 15);
                int byte = (kk * 2) ^ ((nrow & 7) << 4);
                bfr[nf] = *reinterpret_cast<const short8v*>((char*)Ws + nrow * (BK * 2) + byte);
            }
            #pragma unroll
            for (int nf = 0; nf < 4; nf++)
                acc[nf] = __builtin_amdgcn_mfma_f32_16x16x32_bf16(afr, bfr[nf], acc[nf], 0, 0, 0);
        }
        __syncthreads();
    }
    #pragma unroll
    for (int nf = 0; nf < 4; nf++) {
        #pragma unroll
        for (int r = 0; r < 4; r++) {
            int row = m0 + wid * 16 + (lane >> 4) * 4 + r;
            int cl = head * 64 + nf * 16 + (lane & 15);
            if (row < M) {
                float v = acc[nf][r] + bias[cl];
                v = v > 0.f ? v : __expf(v) - 1.f;   // ELU
                g1b[(size_t)row * 256 + cl] = f2bf(v);
            }
        }
    }
}

// ---------------- GEMM + LayerNorm (BM=64, BN=128 full row) -> catb[:, coloff..] ----------------
template<int K>
__global__ __launch_bounds__(256) void gemm_ln_kernel(const unsigned short* __restrict__ A,
                                                      const unsigned short* __restrict__ WT,
                                                      const float* __restrict__ bias,
                                                      const float* __restrict__ gw,
                                                      const float* __restrict__ gb,
                                                      unsigned short* __restrict__ catb,
                                                      int coloff, int M) {
    constexpr int BM = 64, BN = 128, BK = 64;
    __shared__ unsigned short As[BM * BK];
    __shared__ unsigned short Ws[BN * BK];
    int tid = threadIdx.x;
    int wid = tid >> 6, lane = tid & 63;
    int m0 = blockIdx.x * BM;

    f32x4 acc[8] = {};

    for (int k0 = 0; k0 < K; k0 += BK) {
        for (int i = tid; i < BM * (BK / 8); i += 256) {
            int row = i >> 3;
            int kk = (i & 7) * 8;
            int gr = m0 + row;
            short8v v = short8v{0, 0, 0, 0, 0, 0, 0, 0};
            if (gr < M) v = *reinterpret_cast<const short8v*>(&A[(size_t)gr * K + k0 + kk]);
            int byte = (kk * 2) ^ ((row & 7) << 4);
            *reinterpret_cast<short8v*>((char*)As + row * (BK * 2) + byte) = v;
        }
        for (int i = tid; i < BN * (BK / 8); i += 256) {
            int nrow = i >> 3;
            int kk = (i & 7) * 8;
            short8v v = *reinterpret_cast<const short8v*>(&WT[(size_t)nrow * K + k0 + kk]);
            int byte = (kk * 2) ^ ((nrow & 7) << 4);
            *reinterpret_cast<short8v*>((char*)Ws + nrow * (BK * 2) + byte) = v;
        }
        __syncthreads();
        #pragma unroll
        for (int kc = 0; kc < BK; kc += 32) {
            short8v afr, bfr[8];
            int kk = kc + (lane >> 4) * 8;
            {
                int row = wid * 16 + (lane & 15);
                int byte = (kk * 2) ^ ((row & 7) << 4);
                afr = *reinterpret_cast<const short8v*>((char*)As + row * (BK * 2) + byte);
            }
            #pragma unroll
            for (int nf = 0; nf < 8; nf++) {
                int nrow = nf * 16 + (lane & 15);
                int byte = (kk * 2) ^ ((nrow & 7) << 4);
                bfr[nf] = *reinterpret_cast<const short8v*>((char*)Ws + nrow * (BK * 2) + byte);
            }
            #pragma unroll
            for (int nf = 0; nf < 8; nf++)
                acc[nf] = __builtin_amdgcn_mfma_f32_16x16x32_bf16(afr, bfr[nf], acc[nf], 0, 0, 0);
        }
        __syncthreads();
    }
    // epilogue: +bias, LN over 128 cols (16-lane group holds full row), bf16 store
    int cb = lane & 15;
    float gwv[8], gbv[8], bv[8];
    #pragma unroll
    for (int nf = 0; nf < 8; nf++) {
        int c = nf * 16 + cb;
        gwv[nf] = gw[c]; gbv[nf] = gb[c]; bv[nf] = bias[c];
    }
    #pragma unroll
    for (int r = 0; r < 4; r++) {
        int row = m0 + wid * 16 + (lane >> 4) * 4 + r;
        float v[8]; float sm = 0.f, sq = 0.f;
        #pragma unroll
        for (int nf = 0; nf < 8; nf++) {
            v[nf] = acc[nf][r] + bv[nf];
            sm += v[nf]; sq += v[nf] * v[nf];
        }
        #pragma unroll
        for (int o = 1; o < 16; o <<= 1) { sm += __shfl_xor(sm, o, 64); sq += __shfl_xor(sq, o, 64); }
        float mu = sm * (1.f / 128.f);
        float var = sq * (1.f / 128.f) - mu * mu;
        float rs = rsqrtf(var + EPS);
        if (row < M) {
            #pragma unroll
            for (int nf = 0; nf < 8; nf++)
                catb[(size_t)row * 256 + coloff + nf * 16 + cb] =
                    f2bf((v[nf] - mu) * rs * gwv[nf] + gbv[nf]);
        }
    }
}

// ---------------- alpha from features: as_/ad_[n,4] = F[n,K] @ walpha[K][8] ----------------
template<int K>
__global__ __launch_bounds__(256) void alpha_x_kernel(const unsigned short* __restrict__ F,
                                                      const float* __restrict__ wa,
                                                      float* __restrict__ as_, float* __restrict__ ad_, int n) {
    constexpr int PL = K / 64;
    int wid = threadIdx.x >> 6, lane = threadIdx.x & 63;
    int node = blockIdx.x * 4 + wid;
    if (node >= n) return;
    float p[8] = {0, 0, 0, 0, 0, 0, 0, 0};
    const unsigned short* fr = F + (size_t)node * K + lane * PL;
    #pragma unroll
    for (int j = 0; j < PL; j++) {
        float v = bf2f(fr[j]);
        const float4* w4 = reinterpret_cast<const float4*>(wa + (size_t)(lane * PL + j) * 8);
        float4 wA = w4[0], wB = w4[1];
        p[0] += v * wA.x; p[1] += v * wA.y; p[2] += v * wA.z; p[3] += v * wA.w;
        p[4] += v * wB.x; p[5] += v * wB.y; p[6] += v * wB.z; p[7] += v * wB.w;
    }
    #pragma unroll
    for (int o = 1; o < 64; o <<= 1) {
        #pragma unroll
        for (int t = 0; t < 8; t++) p[t] += __shfl_xor(p[t], o, 64);
    }
    if (lane == 0) {
        #pragma unroll
        for (int t = 0; t < 8; t++) {
            if (t & 1) ad_[(size_t)node * 4 + (t >> 1)] = p[t];
            else       as_[(size_t)node * 4 + (t >> 1)] = p[t];
        }
    }
}

// ---------------- merged layer1: GCN P(x) aggregate + GAT-l1 aggregate (ONE gather stream) ----------------
__global__ __launch_bounds__(256) void prop1_agg1_kernel(const unsigned short* __restrict__ xb,   // [n][128]
                                                         const float* __restrict__ dis,
                                                         const float* __restrict__ as_,
                                                         const float* __restrict__ ad_,
                                                         const int* __restrict__ rowptr,
                                                         const int* __restrict__ col,
                                                         unsigned short* __restrict__ aggx,       // [n][128] = P(x)
                                                         unsigned short* __restrict__ agg,        // [n][512]
                                                         int n) {
    constexpr int CAP = 64;
    __shared__ float ex[4][CAP][4];
    __shared__ int scol[4][CAP];
    int wid = threadIdx.x >> 6, lane = threadIdx.x & 63;
    int node = blockIdx.x * 4 + wid;
    if (node >= n) return;
    int b0 = rowptr[node];
    int cnt = rowptr[node + 1] - b0;
    float4 adv = *reinterpret_cast<const float4*>(&ad_[(size_t)node * 4]);
    float p0 = 0, p1 = 0, p2 = 0, p3 = 0;
    for (int i = lane; i <= cnt; i += 64) {
        int s = (i == cnt) ? node : col[b0 + i];
        float4 asv = *reinterpret_cast<const float4*>(&as_[(size_t)s * 4]);
        float e0 = asv.x + adv.x; e0 = e0 > 0.f ? e0 : NEG * e0; float x0 = __expf(e0);
        float e1 = asv.y + adv.y; e1 = e1 > 0.f ? e1 : NEG * e1; float x1 = __expf(e1);
        float e2 = asv.z + adv.z; e2 = e2 > 0.f ? e2 : NEG * e2; float x2 = __expf(e2);
        float e3 = asv.w + adv.w; e3 = e3 > 0.f ? e3 : NEG * e3; float x3 = __expf(e3);
        if (i < CAP) {
            ex[wid][i][0] = x0; ex[wid][i][1] = x1; ex[wid][i][2] = x2; ex[wid][i][3] = x3;
            scol[wid][i] = s;
        }
        p0 += x0; p1 += x1; p2 += x2; p3 += x3;
    }
    #pragma unroll
    for (int o = 1; o < 64; o <<= 1) {
        p0 += __shfl_xor(p0, o, 64); p1 += __shfl_xor(p1, o, 64);
        p2 += __shfl_xor(p2, o, 64); p3 += __shfl_xor(p3, o, 64);
    }
    float inv0 = 1.f / p0, inv1 = 1.f / p1, inv2 = 1.f / p2, inv3 = 1.f / p3;
    for (int i = lane; i <= cnt && i < CAP; i += 64) {
        ex[wid][i][0] *= inv0; ex[wid][i][1] *= inv1;
        ex[wid][i][2] *= inv2; ex[wid][i][3] *= inv3;
    }
    __builtin_amdgcn_wave_barrier();

    auto fetchw = [&](int i, int &s, float4 &w) {
        if (i < CAP) {
            s = scol[wid][i];
            w = *reinterpret_cast<const float4*>(&ex[wid][i][0]);
        } else {
            s = (i == cnt) ? node : col[b0 + i];
            float4 asv = *reinterpret_cast<const float4*>(&as_[(size_t)s * 4]);
            float e0 = asv.x + adv.x; e0 = e0 > 0.f ? e0 : NEG * e0;
            float e1 = asv.y + adv.y; e1 = e1 > 0.f ? e1 : NEG * e1;
            float e2 = asv.z + adv.z; e2 = e2 > 0.f ? e2 : NEG * e2;
            float e3 = asv.w + adv.w; e3 = e3 > 0.f ? e3 : NEG * e3;
            w = make_float4(__expf(e0) * inv0, __expf(e1) * inv1,
                            __expf(e2) * inv2, __expf(e3) * inv3);
        }
    };

    f32x2 g2 = {0.f, 0.f};
    f32x2 ac2[4] = {};
    int total = cnt + 1;
    int i = 0;
    for (; i + 1 < total; i += 2) {
        int s0, s1; float4 wa, wb;
        fetchw(i, s0, wa);
        fetchw(i + 1, s1, wb);
        float ds0 = dis[s0], ds1 = dis[s1];
        unsigned gv0 = *reinterpret_cast<const unsigned*>(&xb[(size_t)s0 * 128 + lane * 2]);
        unsigned gv1 = *reinterpret_cast<const unsigned*>(&xb[(size_t)s1 * 128 + lane * 2]);
        f32x2 f0, f1;
        f0.x = bf2f((unsigned short)(gv0 & 0xFFFF)); f0.y = bf2f((unsigned short)(gv0 >> 16));
        f1.x = bf2f((unsigned short)(gv1 & 0xFFFF)); f1.y = bf2f((unsigned short)(gv1 >> 16));
        g2 += ds0 * f0;      g2 += ds1 * f1;
        ac2[0] += wa.x * f0; ac2[0] += wb.x * f1;
        ac2[1] += wa.y * f0; ac2[1] += wb.y * f1;
        ac2[2] += wa.z * f0; ac2[2] += wb.z * f1;
        ac2[3] += wa.w * f0; ac2[3] += wb.w * f1;
    }
    if (i < total) {
        int s0; float4 wa;
        fetchw(i, s0, wa);
        float ds0 = dis[s0];
        unsigned gv0 = *reinterpret_cast<const unsigned*>(&xb[(size_t)s0 * 128 + lane * 2]);
        f32x2 f0;
        f0.x = bf2f((unsigned short)(gv0 & 0xFFFF)); f0.y = bf2f((unsigned short)(gv0 >> 16));
        g2 += ds0 * f0;
        ac2[0] += wa.x * f0; ac2[1] += wa.y * f0;
        ac2[2] += wa.z * f0; ac2[3] += wa.w * f0;
    }
    float dd = dis[node];
    unsigned pkg = (unsigned)f2bf(dd * g2.x) | ((unsigned)f2bf(dd * g2.y) << 16);
    *reinterpret_cast<unsigned*>(&aggx[(size_t)node * 128 + lane * 2]) = pkg;
    #pragma unroll
    for (int h = 0; h < 4; h++) {
        unsigned pk = (unsigned)f2bf(ac2[h].x) | ((unsigned)f2bf(ac2[h].y) << 16);
        *reinterpret_cast<unsigned*>(&agg[(size_t)node * 512 + h * 128 + lane * 2]) = pk;
    }
}

// ---------------- merged layer2: GCN P(h) aggregate + GAT-l2 aggregate ----------------
// hbs is PRE-SCALED: hbs[s] = dis[s]*h[s], so no dis gather needed here.
__global__ __launch_bounds__(256) void prop2_agg2_kernel(const unsigned short* __restrict__ g1b,  // [n][256]
                                                         const unsigned short* __restrict__ hbs,  // [n][64]
                                                         const float* __restrict__ dis,
                                                         const float* __restrict__ as_,
                                                         const float* __restrict__ ad_,
                                                         const int* __restrict__ rowptr,
                                                         const int* __restrict__ col,
                                                         unsigned short* __restrict__ aggh,       // [n][64] = P(h)
                                                         unsigned short* __restrict__ agg,        // [n][1024]
                                                         int n) {
    constexpr int CAP = 64;
    __shared__ float ex[4][CAP][4];
    __shared__ int scol[4][CAP];
    int wid = threadIdx.x >> 6, lane = threadIdx.x & 63;
    int node = blockIdx.x * 4 + wid;
    if (node >= n) return;
    int b0 = rowptr[node];
    int cnt = rowptr[node + 1] - b0;
    float4 adv = *reinterpret_cast<const float4*>(&ad_[(size_t)node * 4]);
    float p0 = 0, p1 = 0, p2 = 0, p3 = 0;
    for (int i = lane; i <= cnt; i += 64) {
        int s = (i == cnt) ? node : col[b0 + i];
        float4 asv = *reinterpret_cast<const float4*>(&as_[(size_t)s * 4]);
        float e0 = asv.x + adv.x; e0 = e0 > 0.f ? e0 : NEG * e0; float x0 = __expf(e0);
        float e1 = asv.y + adv.y; e1 = e1 > 0.f ? e1 : NEG * e1; float x1 = __expf(e1);
        float e2 = asv.z + adv.z; e2 = e2 > 0.f ? e2 : NEG * e2; float x2 = __expf(e2);
        float e3 = asv.w + adv.w; e3 = e3 > 0.f ? e3 : NEG * e3; float x3 = __expf(e3);
        if (i < CAP) {
            ex[wid][i][0] = x0; ex[wid][i][1] = x1; ex[wid][i][2] = x2; ex[wid][i][3] = x3;
            scol[wid][i] = s;
        }
        p0 += x0; p1 += x1; p2 += x2; p3 += x3;
    }
    #pragma unroll
    for (int o = 1; o < 64; o <<= 1) {
        p0 += __shfl_xor(p0, o, 64); p1 += __shfl_xor(p1, o, 64);
        p2 += __shfl_xor(p2, o, 64); p3 += __shfl_xor(p3, o, 64);
    }
    float inv0 = 1.f / p0, inv1 = 1.f / p1, inv2 = 1.f / p2, inv3 = 1.f / p3;
    for (int i = lane; i <= cnt && i < CAP; i += 64) {
        ex[wid][i][0] *= inv0; ex[wid][i][1] *= inv1;
        ex[wid][i][2] *= inv2; ex[wid][i][3] *= inv3;
    }
    __builtin_amdgcn_wave_barrier();

    auto fetchw = [&](int i, int &s, float4 &w) {
        if (i < CAP) {
            s = scol[wid][i];
            w = *reinterpret_cast<const float4*>(&ex[wid][i][0]);
        } else {
            s = (i == cnt) ? node : col[b0 + i];
            float4 asv = *reinterpret_cast<const float4*>(&as_[(size_t)s * 4]);
            float e0 = asv.x + adv.x; e0 = e0 > 0.f ? e0 : NEG * e0;
            float e1 = asv.y + adv.y; e1 = e1 > 0.f ? e1 : NEG * e1;
            float e2 = asv.z + adv.z; e2 = e2 > 0.f ? e2 : NEG * e2;
            float e3 = asv.w + adv.w; e3 = e3 > 0.f ? e3 : NEG * e3;
            w = make_float4(__expf(e0) * inv0, __expf(e1) * inv1,
                            __expf(e2) * inv2, __expf(e3) * inv3);
        }
    };

    float hacc = 0.f;
    f32x2 ac2[4][2] = {};
    int total = cnt + 1;
    int i = 0;
    for (; i + 1 < total; i += 2) {
        int s0, s1; float4 wa, wb;
        fetchw(i, s0, wa);
        fetchw(i + 1, s1, wb);
        short4v v0 = *reinterpret_cast<const short4v*>(&g1b[(size_t)s0 * 256 + lane * 4]);
        short4v v1 = *reinterpret_cast<const short4v*>(&g1b[(size_t)s1 * 256 + lane * 4]);
        float hv0 = bf2f(hbs[(size_t)s0 * 64 + lane]);
        float hv1 = bf2f(hbs[(size_t)s1 * 64 + lane]);
        hacc += hv0 + hv1;
        f32x2 fa0, fb0, fa1, fb1;
        fa0.x = bf2f((unsigned short)v0[0]); fa0.y = bf2f((unsigned short)v0[1]);
        fb0.x = bf2f((unsigned short)v0[2]); fb0.y = bf2f((unsigned short)v0[3]);
        fa1.x = bf2f((unsigned short)v1[0]); fa1.y = bf2f((unsigned short)v1[1]);
        fb1.x = bf2f((unsigned short)v1[2]); fb1.y = bf2f((unsigned short)v1[3]);
        ac2[0][0] += wa.x * fa0; ac2[0][1] += wa.x * fb0;
        ac2[0][0] += wb.x * fa1; ac2[0][1] += wb.x * fb1;
        ac2[1][0] += wa.y * fa0; ac2[1][1] += wa.y * fb0;
        ac2[1][0] += wb.y * fa1; ac2[1][1] += wb.y * fb1;
        ac2[2][0] += wa.z * fa0; ac2[2][1] += wa.z * fb0;
        ac2[2][0] += wb.z * fa1; ac2[2][1] += wb.z * fb1;
        ac2[3][0] += wa.w * fa0; ac2[3][1] += wa.w * fb0;
        ac2[3][0] += wb.w * fa1; ac2[3][1] += wb.w * fb1;
    }
    if (i < total) {
        int s0; float4 wa;
        fetchw(i, s0, wa);
        short4v v0 = *reinterpret_cast<const short4v*>(&g1b[(size_t)s0 * 256 + lane * 4]);
        hacc += bf2f(hbs[(size_t)s0 * 64 + lane]);
        f32x2 fa0, fb0;
        fa0.x = bf2f((unsigned short)v0[0]); fa0.y = bf2f((unsigned short)v0[1]);
        fb0.x = bf2f((unsigned short)v0[2]); fb0.y = bf2f((unsigned short)v0[3]);
        ac2[0][0] += wa.x * fa0; ac2[0][1] += wa.x * fb0;
        ac2[1][0] += wa.y * fa0; ac2[1][1] += wa.y * fb0;
        ac2[2][0] += wa.z * fa0; ac2[2][1] += wa.z * fb0;
        ac2[3][0] += wa.w * fa0; ac2[3][1] += wa.w * fb0;
    }
    float dd = dis[node];
    aggh[(size_t)node * 64 + lane] = f2bf(dd * hacc);
    #pragma unroll
    for (int h = 0; h < 4; h++) {
        short4v o4;
        o4[0] = (short)f2bf(ac2[h][0].x); o4[1] = (short)f2bf(ac2[h][0].y);
        o4[2] = (short)f2bf(ac2[h][1].x); o4[3] = (short)f2bf(ac2[h][1].y);
        *reinterpret_cast<short4v*>(&agg[(size_t)node * 1024 + h * 256 + lane * 4]) = o4;
    }
}

// ---------------- launch ----------------
extern "C" void kernel_launch(void* const* d_in, const int* in_sizes, int n_in,
                              void* d_out, int out_size, void* d_ws, size_t ws_size,
                              hipStream_t stream) {
    const float* x      = (const float*)d_in[0];
    const int*   ei     = (const int*)d_in[1];
    const float* W_gcn1 = (const float*)d_in[2];
    const float* b_gcn1 = (const float*)d_in[3];
    const float* W_gcn2 = (const float*)d_in[4];
    const float* b_gcn2 = (const float*)d_in[5];
    const float* W_gat1 = (const float*)d_in[6];
    const float* a_src1 = (const float*)d_in[7];
    const float* a_dst1 = (const float*)d_in[8];
    const float* b_gat1 = (const float*)d_in[9];
    const float* W_gat2 = (const float*)d_in[10];
    const float* a_src2 = (const float*)d_in[11];
    const float* a_dst2 = (const float*)d_in[12];
    const float* b_gat2 = (const float*)d_in[13];
    const float* g_gcn  = (const float*)d_in[14];
    const float* bt_gcn = (const float*)d_in[15];
    const float* g_gat  = (const float*)d_in[16];
    const float* bt_gat = (const float*)d_in[17];
    const float* W_fuse = (const float*)d_in[18];
    const float* b_fuse = (const float*)d_in[19];
    float* out = (float*)d_out;

    const int n = in_sizes[0] / 128;
    const int E = in_sizes[1] / 2;

    char* ws = (char*)d_ws;
    size_t off = 0;
    auto alloc = [&](size_t bytes) -> char* {
        char* p = ws + off;
        off += (bytes + 255) & ~(size_t)255;
        return p;
    };
    int*   cnt      = (int*)alloc((size_t)n * 4);
    int*   rowptr   = (int*)alloc((size_t)(n + 1) * 4);
    int*   cursor   = (int*)alloc((size_t)n * 4);
    int*   col      = (int*)alloc((size_t)E * 4);
    int*   partials = (int*)alloc(64 * 4);
    float* dis      = (float*)alloc((size_t)n * 4);
    float* as_      = (float*)alloc((size_t)n * 16);
    float* ad_      = (float*)alloc((size_t)n * 16);
    float* wa1      = (float*)alloc(1024 * 4);
    float* wa2      = (float*)alloc(2048 * 4);
    unsigned short* xb   = (unsigned short*)alloc((size_t)n * 128 * 2);
    unsigned short* WT1  = (unsigned short*)alloc(8192 * 2);
    unsigned short* WT2  = (unsigned short*)alloc(8192 * 2);
    unsigned short* WT3  = (unsigned short*)alloc(32768 * 2);
    unsigned short* WTF  = (unsigned short*)alloc(131072 * 2);
    unsigned short* WT5  = (unsigned short*)alloc(32768 * 2);
    // BIG (n*1024 bf16 = agg2b). Sub-lease while agg2 not yet live:
    //   agg1b = BIG[0, n*512) ; aggx1 = BIG[n*512, n*640)
    // hbs/aggh OUTSIDE BIG (hbs read while agg2b is written).
    unsigned short* BIG   = (unsigned short*)alloc((size_t)n * 1024 * 2);
    unsigned short* agg2b = BIG;
    unsigned short* agg1b = BIG;
    unsigned short* aggx1 = BIG + (size_t)n * 512;
    unsigned short* hbs   = (unsigned short*)alloc((size_t)n * 64 * 2);
    unsigned short* aggh  = (unsigned short*)alloc((size_t)n * 64 * 2);
    unsigned short* g1b   = (unsigned short*)alloc((size_t)n * 256 * 2);
    unsigned short* catb  = (unsigned short*)alloc((size_t)n * 256 * 2);

    const int nb = (n + 1023) / 1024;

    // setup
    hipMemsetAsync(cnt, 0, (size_t)n * 4, stream);
    {
        long long total = (long long)E + (long long)n * 32 + 212992 + 3072;
        int blocks = (int)((total + 255) / 256);
        setup_kernel<<<blocks, 256, 0, stream>>>(ei, cnt, E, n, x, xb,
            W_gcn1, W_gcn2, W_gat1, W_gat2, W_fuse, WT1, WT2, WT3, WTF, WT5,
            a_src1, a_dst1, a_src2, a_dst2, wa1, wa2);
    }
    partial_kernel<<<nb, 256, 0, stream>>>(cnt, partials, n);
    scanp_kernel<<<1, 64, 0, stream>>>(partials, nb);
    scan2_kernel<<<nb, 256, 0, stream>>>(cnt, partials, rowptr, cursor, dis, n, E);
    fill_kernel<<<(E + 255) / 256, 256, 0, stream>>>(ei, cursor, col, E);

    int gm64 = (n + 63) / 64;
    int gn4 = (n + 3) / 4;

    // layer 1: one gather pass over xb feeds both branches
    alpha_x_kernel<128><<<gn4, 256, 0, stream>>>(xb, wa1, as_, ad_, n);
    prop1_agg1_kernel<<<gn4, 256, 0, stream>>>(xb, dis, as_, ad_, rowptr, col, aggx1, agg1b, n);
    // post-GEMMs: hbs = dis * relu(P(x)@W1 + b1); g1 = ELU(agg1@W3 + b_gat1)
    mfma_gemm<64, 128, 64, true, 1><<<dim3(gm64, 1), 256, 0, stream>>>(aggx1, WT1, b_gcn1, dis, hbs, n);
    gemm_head_kernel<<<dim3(gm64, 4), 256, 0, stream>>>(agg1b, WT3, b_gat1, g1b, n);
    // layer 2
    alpha_x_kernel<256><<<gn4, 256, 0, stream>>>(g1b, wa2, as_, ad_, n);
    prop2_agg2_kernel<<<gn4, 256, 0, stream>>>(g1b, hbs, dis, as_, ad_, rowptr, col, aggh, agg2b, n);
    // post-GEMMs with fused LN -> catb halves
    gemm_ln_kernel<64><<<gm64, 256, 0, stream>>>(aggh, WT2, b_gcn2, g_gcn, bt_gcn, catb, 0, n);
    gemm_ln_kernel<1024><<<gm64, 256, 0, stream>>>(agg2b, WTF, b_gat2, g_gat, bt_gat, catb, 128, n);

    // fuse
    mfma_gemm<64, 256, 128, false, 0><<<dim3(gm64, 2), 256, 0, stream>>>(catb, WT5, b_fuse, nullptr, out, n);
}